// Round 13
// baseline (4875.995 us; speedup 1.0000x reference)
//
#include <hip/hip_runtime.h>
#include <stdint.h>
#include <stddef.h>

// Reverse LSTM: T=256, B=64, D=H=1024.
// Phase 0: cast x, W_ih to bf16.
// Phase 1: P[t][n][b] = bf16( x@W_ih^T + b_ih + b_hh )  (bf16 MFMA GEMM, proven)
// Phase 2: *** 256 chained REGULAR kernel launches *** (no cooperative launch,
//   no device-wide barrier, no atomics/flags/asm). Each step kernel:
//   gates = P(t) + h @ W_hh_slice^T with BOTH MFMA operands streamed from L2
//   (W_hh pre-permuted into fragment order; h 128KB double-buffered in ws),
//   pointwise in f32 with c-state in a global buffer, h(t) published as plain
//   bf16 stores. Cross-step visibility = kernel dispatch boundary (HW-guaranteed).

typedef unsigned short u16;
typedef __attribute__((ext_vector_type(4))) unsigned short u16x4;
typedef __attribute__((ext_vector_type(8))) short short8;
typedef __attribute__((ext_vector_type(4))) float f32x4;

#define T_LEN 256
#define YS_ELEMS (256 * 64 * 1024)  // 16777216

__device__ __forceinline__ u16 f2bf(float f) {
  union { float f; unsigned int i; } v; v.f = f;
  unsigned int r = v.i + 0x7FFFu + ((v.i >> 16) & 1u);  // RNE
  return (u16)(r >> 16);
}
__device__ __forceinline__ float bf2f(u16 u) {
  union { unsigned int i; float f; } v; v.i = ((unsigned int)u) << 16; return v.f;
}
__device__ __forceinline__ void gload_lds16(const void* g, void* l) {
  __builtin_amdgcn_global_load_lds(
      (const __attribute__((address_space(1))) unsigned int*)g,
      (__attribute__((address_space(3))) unsigned int*)l, 16, 0, 0);
}
__device__ __forceinline__ float sigm_fast(float x) { return 1.f / (1.f + __expf(-x)); }

// ---------------- Phase 0: f32 -> bf16 cast ----------------
__global__ void cast_f32_bf16(const float* __restrict__ src, u16* __restrict__ dst, int n4) {
  int i = blockIdx.x * blockDim.x + threadIdx.x;
  const int stride = gridDim.x * blockDim.x;
  for (; i < n4; i += stride) {
    float4 v = ((const float4*)src)[i];
    u16x4 o;
    o[0] = f2bf(v.x); o[1] = f2bf(v.y); o[2] = f2bf(v.z); o[3] = f2bf(v.w);
    ((u16x4*)dst)[i] = o;
  }
}

// W_hh f32[4096][1024] -> Wp bf16 in fragment order:
// Wp[((j>>4)*64 + g*16 + (j&15))][k] = bf16(W_hh[g*1024 + j][k])
__global__ void perm_cast_whh(const float* __restrict__ W, u16* __restrict__ Wp) {
  int i = blockIdx.x * blockDim.x + threadIdx.x;   // 524288 threads, 8 elems each
  const int r = i >> 7;          // input row 0..4095
  const int kc = (i & 127) * 8;  // k offset
  const int g = r >> 10, j = r & 1023;
  const int orow = ((j >> 4) << 6) + (g << 4) + (j & 15);
  const float4 v0 = *(const float4*)(W + (size_t)r * 1024 + kc);
  const float4 v1 = *(const float4*)(W + (size_t)r * 1024 + kc + 4);
  short8 pk;
  pk[0] = (short)f2bf(v0.x); pk[1] = (short)f2bf(v0.y);
  pk[2] = (short)f2bf(v0.z); pk[3] = (short)f2bf(v0.w);
  pk[4] = (short)f2bf(v1.x); pk[5] = (short)f2bf(v1.y);
  pk[6] = (short)f2bf(v1.z); pk[7] = (short)f2bf(v1.w);
  *(short8*)(Wp + (size_t)orow * 1024 + kc) = pk;
}

// diagnostic canary: out[0] = 100 (step t=0 kernel overwrites it on success)
__global__ void canary_k(float* __restrict__ out) { out[0] = 100.0f; }

// ---------------- Phase 1: pregate GEMM (proven, unchanged) ----------------
__global__ __launch_bounds__(256, 2) void gemm_pre(
    const u16* __restrict__ X, const u16* __restrict__ Wih,
    const float* __restrict__ bih, const float* __restrict__ bhh,
    u16* __restrict__ Pout)
{
  __shared__ u16 As[128 * 64];
  __shared__ u16 Bs[128 * 64];
  const int tid = threadIdx.x;
  const int lane = tid & 63;
  const int wid = tid >> 6;
  const int wm = wid & 1, wn = wid >> 1;
  const int Mt = blockIdx.x, Nt = blockIdx.y;

  f32x4 acc[4][4] = {};
  const int rsub = lane >> 3;
  const int src_chunk = (lane & 7) ^ rsub;

  for (int it = 0; it < 16; ++it) {
    const int k0 = it * 64;
    #pragma unroll
    for (int q = 0; q < 4; ++q) {
      const int j = wid * 4 + q;
      const int row_local = j * 8 + rsub;
      const u16* ga = X   + ((size_t)(Mt * 128 + row_local)) * 1024 + k0 + src_chunk * 8;
      const u16* gb = Wih + ((size_t)(Nt * 128 + row_local)) * 1024 + k0 + src_chunk * 8;
      gload_lds16(ga, (char*)As + j * 1024);
      gload_lds16(gb, (char*)Bs + j * 1024);
    }
    __syncthreads();
    #pragma unroll
    for (int ks = 0; ks < 2; ++ks) {
      short8 af[4], bfv[4];
      #pragma unroll
      for (int f = 0; f < 4; ++f) {
        const int ra = wm * 64 + f * 16 + (lane & 15);
        const int rb = wn * 64 + f * 16 + (lane & 15);
        const int kc = ks * 4 + (lane >> 4);
        af[f]  = *(const short8*)((const char*)As + ra * 128 + ((kc ^ (ra & 7)) << 4));
        bfv[f] = *(const short8*)((const char*)Bs + rb * 128 + ((kc ^ (rb & 7)) << 4));
      }
      #pragma unroll
      for (int fm = 0; fm < 4; ++fm)
        #pragma unroll
        for (int fn = 0; fn < 4; ++fn)
          acc[fm][fn] = __builtin_amdgcn_mfma_f32_16x16x32_bf16(af[fm], bfv[fn], acc[fm][fn], 0, 0, 0);
    }
    __syncthreads();
  }

  const int t_out = Mt * 2 + wm;
  #pragma unroll
  for (int fn = 0; fn < 4; ++fn) {
    const int n = Nt * 128 + wn * 64 + fn * 16 + (lane & 15);
    const float bias = bih[n] + bhh[n];
    #pragma unroll
    for (int fm = 0; fm < 4; ++fm) {
      const int b = fm * 16 + ((lane >> 4) << 2);
      u16x4 o;
      #pragma unroll
      for (int r = 0; r < 4; ++r) o[r] = f2bf(acc[fm][fn][r] + bias);
      *(u16x4*)(Pout + ((size_t)t_out * 4096 + n) * 64 + b) = o;
    }
  }
}

// ---------------- Phase 2: one time step per launch ----------------
// 64 WGs x 256 threads. WG w owns units [16w,16w+16). LDS: GX 16KB only.
// Operands streamed from L2: Wp (fragment-ordered, L2-hot), h (128KB).
__global__ __launch_bounds__(256) void lstm_step(
    const u16* __restrict__ Pt,     // P slab for this t: [4096][64] bf16
    const u16* __restrict__ Wp,     // permuted W_hh bf16
    const u16* __restrict__ hin,    // h(prev) [64][1024] bf16
    u16* __restrict__ hout,         // h(new)  [64][1024] bf16
    float* __restrict__ cbuf,       // c state [64][1024] f32 (in-place)
    float* __restrict__ out,
    int t, int last)
{
  __shared__ float GX[4096];

  const int tid = threadIdx.x;
  const int lane = tid & 63;
  const int wid = tid >> 6;
  const int wg = blockIdx.x;

  const int wm = wid & 1;
  const int wn = wid >> 1;
  const int row0 = wm * 32 + (lane & 15);
  const int row1 = row0 + 16;
  const int rs0 = wn * 32 + (lane & 15);
  const int rs1 = rs0 + 16;
  const u16* Wsl = Wp + (size_t)wg * 65536;   // 64 slice rows x 1024

  f32x4 acc00 = {}, acc01 = {}, acc10 = {}, acc11 = {};

  #pragma unroll
  for (int kabs = 0; kabs < 32; ++kabs) {
    const int ko = kabs * 32 + ((lane >> 4) << 3);
    const short8 a0 = *(const short8*)(hin + (size_t)row0 * 1024 + ko);
    const short8 a1 = *(const short8*)(hin + (size_t)row1 * 1024 + ko);
    const short8 b0 = *(const short8*)(Wsl + (size_t)rs0 * 1024 + ko);
    const short8 b1 = *(const short8*)(Wsl + (size_t)rs1 * 1024 + ko);
    acc00 = __builtin_amdgcn_mfma_f32_16x16x32_bf16(a0, b0, acc00, 0, 0, 0);
    acc01 = __builtin_amdgcn_mfma_f32_16x16x32_bf16(a0, b1, acc01, 0, 0, 0);
    acc10 = __builtin_amdgcn_mfma_f32_16x16x32_bf16(a1, b0, acc10, 0, 0, 0);
    acc11 = __builtin_amdgcn_mfma_f32_16x16x32_bf16(a1, b1, acc11, 0, 0, 0);
  }

  // gate exchange through LDS (R7-proven swizzled layout)
  {
    const int uu = lane & 15;
    #pragma unroll
    for (int mi = 0; mi < 2; ++mi) {
      const int bb = wm * 32 + mi * 16 + ((lane >> 4) << 2);
      const f32x4 vlo = (mi == 0) ? acc00 : acc10;
      const f32x4 vhi = (mi == 0) ? acc01 : acc11;
      const int g0 = wn * 2;
      *(f32x4*)((char*)GX + ((((g0 * 16 + uu) * 64 + bb) << 2) ^ ((uu & 7) << 4))) = vlo;
      *(f32x4*)((char*)GX + (((((g0 + 1) * 16 + uu) * 64 + bb) << 2) ^ ((uu & 7) << 4))) = vhi;
    }
  }
  __syncthreads();

  // pointwise: unit u, batches b0..b0+3 (R7-proven roles & math)
  const int u = tid & 15;
  const int b0 = (tid >> 4) << 2;
  const int jh = wg * 16 + u;

  const f32x4 vi = *(const f32x4*)((char*)GX + ((((0 * 16 + u) * 64 + b0) << 2) ^ ((u & 7) << 4)));
  const f32x4 vf = *(const f32x4*)((char*)GX + ((((1 * 16 + u) * 64 + b0) << 2) ^ ((u & 7) << 4)));
  const f32x4 vg = *(const f32x4*)((char*)GX + ((((2 * 16 + u) * 64 + b0) << 2) ^ ((u & 7) << 4)));
  const f32x4 vo = *(const f32x4*)((char*)GX + ((((3 * 16 + u) * 64 + b0) << 2) ^ ((u & 7) << 4)));

  const u16x4 pi = *(const u16x4*)(Pt + (size_t)(0 * 1024 + jh) * 64 + b0);
  const u16x4 pf = *(const u16x4*)(Pt + (size_t)(1 * 1024 + jh) * 64 + b0);
  const u16x4 pg = *(const u16x4*)(Pt + (size_t)(2 * 1024 + jh) * 64 + b0);
  const u16x4 po = *(const u16x4*)(Pt + (size_t)(3 * 1024 + jh) * 64 + b0);

  u16x4 hb;
  #pragma unroll
  for (int r = 0; r < 4; ++r) {
    const float xi = vi[r] + bf2f(pi[r]);
    const float xf = vf[r] + bf2f(pf[r]);
    const float xg = vg[r] + bf2f(pg[r]);
    const float xo = vo[r] + bf2f(po[r]);
    const float ig = sigm_fast(xi);
    const float fg = sigm_fast(xf);
    const float og = sigm_fast(xo);
    const size_t cidx = (size_t)(b0 + r) * 1024 + jh;
    const float cn = fg * cbuf[cidx] + ig * tanhf(xg);
    const float hv = og * tanhf(cn);
    cbuf[cidx] = cn;
    hb[r] = f2bf(hv);
    out[((size_t)t * 64 + b0 + r) * 1024 + jh] = hv;   // ys
    if (last) {
      out[YS_ELEMS + (size_t)(b0 + r) * 1024 + jh] = hv;          // hT
      out[YS_ELEMS + 65536 + (size_t)(b0 + r) * 1024 + jh] = cn;  // cT
    }
  }
  *(u16x4*)(hout + (size_t)(b0) * 1024 + jh) = hb;  // wrong row-major? no:
  // hout layout [b][1024]: thread owns (b0..b0+3, jh) -> 4 scalar stores needed.
}

// NOTE: the vector store above would be wrong (h is [b][j]); use scalar stores.
// Corrected in lstm_step2 below — lstm_step is NOT launched.
__global__ __launch_bounds__(256) void lstm_step2(
    const u16* __restrict__ Pt, const u16* __restrict__ Wp,
    const u16* __restrict__ hin, u16* __restrict__ hout,
    float* __restrict__ cbuf, float* __restrict__ out, int t, int last)
{
  __shared__ float GX[4096];

  const int tid = threadIdx.x;
  const int lane = tid & 63;
  const int wid = tid >> 6;
  const int wg = blockIdx.x;

  const int wm = wid & 1;
  const int wn = wid >> 1;
  const int row0 = wm * 32 + (lane & 15);
  const int row1 = row0 + 16;
  const int rs0 = wn * 32 + (lane & 15);
  const int rs1 = rs0 + 16;
  const u16* Wsl = Wp + (size_t)wg * 65536;

  f32x4 acc00 = {}, acc01 = {}, acc10 = {}, acc11 = {};

  #pragma unroll
  for (int kabs = 0; kabs < 32; ++kabs) {
    const int ko = kabs * 32 + ((lane >> 4) << 3);
    const short8 a0 = *(const short8*)(hin + (size_t)row0 * 1024 + ko);
    const short8 a1 = *(const short8*)(hin + (size_t)row1 * 1024 + ko);
    const short8 b0 = *(const short8*)(Wsl + (size_t)rs0 * 1024 + ko);
    const short8 b1 = *(const short8*)(Wsl + (size_t)rs1 * 1024 + ko);
    acc00 = __builtin_amdgcn_mfma_f32_16x16x32_bf16(a0, b0, acc00, 0, 0, 0);
    acc01 = __builtin_amdgcn_mfma_f32_16x16x32_bf16(a0, b1, acc01, 0, 0, 0);
    acc10 = __builtin_amdgcn_mfma_f32_16x16x32_bf16(a1, b0, acc10, 0, 0, 0);
    acc11 = __builtin_amdgcn_mfma_f32_16x16x32_bf16(a1, b1, acc11, 0, 0, 0);
  }

  {
    const int uu = lane & 15;
    #pragma unroll
    for (int mi = 0; mi < 2; ++mi) {
      const int bb = wm * 32 + mi * 16 + ((lane >> 4) << 2);
      const f32x4 vlo = (mi == 0) ? acc00 : acc10;
      const f32x4 vhi = (mi == 0) ? acc01 : acc11;
      const int g0 = wn * 2;
      *(f32x4*)((char*)GX + ((((g0 * 16 + uu) * 64 + bb) << 2) ^ ((uu & 7) << 4))) = vlo;
      *(f32x4*)((char*)GX + (((((g0 + 1) * 16 + uu) * 64 + bb) << 2) ^ ((uu & 7) << 4))) = vhi;
    }
  }
  __syncthreads();

  const int u = tid & 15;
  const int b0 = (tid >> 4) << 2;
  const int jh = wg * 16 + u;

  const f32x4 vi = *(const f32x4*)((char*)GX + ((((0 * 16 + u) * 64 + b0) << 2) ^ ((u & 7) << 4)));
  const f32x4 vf = *(const f32x4*)((char*)GX + ((((1 * 16 + u) * 64 + b0) << 2) ^ ((u & 7) << 4)));
  const f32x4 vg = *(const f32x4*)((char*)GX + ((((2 * 16 + u) * 64 + b0) << 2) ^ ((u & 7) << 4)));
  const f32x4 vo = *(const f32x4*)((char*)GX + ((((3 * 16 + u) * 64 + b0) << 2) ^ ((u & 7) << 4)));

  const u16x4 pi = *(const u16x4*)(Pt + (size_t)(0 * 1024 + jh) * 64 + b0);
  const u16x4 pf = *(const u16x4*)(Pt + (size_t)(1 * 1024 + jh) * 64 + b0);
  const u16x4 pg = *(const u16x4*)(Pt + (size_t)(2 * 1024 + jh) * 64 + b0);
  const u16x4 po = *(const u16x4*)(Pt + (size_t)(3 * 1024 + jh) * 64 + b0);

  #pragma unroll
  for (int r = 0; r < 4; ++r) {
    const float xi = vi[r] + bf2f(pi[r]);
    const float xf = vf[r] + bf2f(pf[r]);
    const float xg = vg[r] + bf2f(pg[r]);
    const float xo = vo[r] + bf2f(po[r]);
    const float ig = sigm_fast(xi);
    const float fg = sigm_fast(xf);
    const float og = sigm_fast(xo);
    const size_t cidx = (size_t)(b0 + r) * 1024 + jh;
    const float cn = fg * cbuf[cidx] + ig * tanhf(xg);
    const float hv = og * tanhf(cn);
    cbuf[cidx] = cn;
    hout[cidx] = f2bf(hv);                              // h(new), [b][j]
    out[((size_t)t * 64 + b0 + r) * 1024 + jh] = hv;    // ys
    if (last) {
      out[YS_ELEMS + cidx] = hv;                        // hT
      out[YS_ELEMS + 65536 + cidx] = cn;                // cT
    }
  }
}

// ---------------- launch ----------------
extern "C" void kernel_launch(void* const* d_in, const int* in_sizes, int n_in,
                              void* d_out, int out_size, void* d_ws, size_t ws_size,
                              hipStream_t stream) {
  const float* x   = (const float*)d_in[0];
  const float* h0  = (const float*)d_in[1];
  const float* c0  = (const float*)d_in[2];
  const float* Wih = (const float*)d_in[3];
  const float* Whh = (const float*)d_in[4];
  const float* bih = (const float*)d_in[5];
  const float* bhh = (const float*)d_in[6];
  float* out = (float*)d_out;

  char* ws = (char*)d_ws;
  u16* x_bf   = (u16*)(ws + 0);           // 32MB, pre-gemm only
  u16* Wp     = (u16*)(ws + 0);           // 8MB, written AFTER gemm_pre (reuses x_bf)
  u16* hbuf   = (u16*)(ws + 8388608);     // 2 x 131072 B
  float* cbuf = (float*)(ws + 8650752);   // 262144 B
  u16* wih_bf = (u16*)(ws + 33554432);    // 8MB
  u16* Pp     = (u16*)(ws + 41943040);    // 128MB

  hipLaunchKernelGGL(cast_f32_bf16, dim3(2048), dim3(256), 0, stream, x,   x_bf,   4194304);
  hipLaunchKernelGGL(cast_f32_bf16, dim3(1024), dim3(256), 0, stream, Wih, wih_bf, 1048576);
  hipLaunchKernelGGL(gemm_pre, dim3(128, 32), dim3(256), 0, stream, x_bf, wih_bf, bih, bhh, Pp);
  // x_bf dead: build Wp, h0, c0 state
  hipLaunchKernelGGL(perm_cast_whh, dim3(2048), dim3(256), 0, stream, Whh, Wp);
  hipLaunchKernelGGL(cast_f32_bf16, dim3(64), dim3(256), 0, stream, h0, hbuf, 16384);
  hipMemcpyAsync(cbuf, c0, 262144, hipMemcpyDeviceToDevice, stream);
  hipLaunchKernelGGL(canary_k, dim3(1), dim3(1), 0, stream, out);

  for (int si = 0; si < 256; ++si) {
    const int t = 255 - si;
    const u16* rb = hbuf + (size_t)(si & 1) * 65536;
    u16* wb = hbuf + (size_t)((si + 1) & 1) * 65536;
    const u16* Pt = Pp + (size_t)t * 262144;
    hipLaunchKernelGGL(lstm_step2, dim3(64), dim3(256), 0, stream,
                       Pt, Wp, rb, wb, cbuf, out, t, (si == 255) ? 1 : 0);
  }
}

// Round 14
// 2955.295 us; speedup vs baseline: 1.6499x; 1.6499x over previous
//
#include <hip/hip_runtime.h>
#include <stdint.h>
#include <stddef.h>

// Reverse LSTM: T=256, B=64, D=H=1024.
// R14 = R12 body (R7-proven persistent recurrence + ys-after-flag edit + canary)
// launched as a REGULAR kernel (hipLaunchKernelGGL) instead of cooperative.
// The flag/poll protocol only needs co-residency: 64 WGs x 1/CU on 256 CUs is
// trivially co-resident on an otherwise-empty GPU. Regular launches cannot be
// silently rejected the way hipLaunchCooperativeKernel was in R8-R12.

typedef unsigned short u16;
typedef __attribute__((ext_vector_type(4))) unsigned short u16x4;
typedef __attribute__((ext_vector_type(8))) short short8;
typedef __attribute__((ext_vector_type(4))) float f32x4;

#define T_LEN 256
#define YS_ELEMS (256 * 64 * 1024)  // 16777216

__device__ __forceinline__ u16 f2bf(float f) {
  union { float f; unsigned int i; } v; v.f = f;
  unsigned int r = v.i + 0x7FFFu + ((v.i >> 16) & 1u);  // RNE
  return (u16)(r >> 16);
}
__device__ __forceinline__ float bf2f(u16 u) {
  union { unsigned int i; float f; } v; v.i = ((unsigned int)u) << 16; return v.f;
}
__device__ __forceinline__ void gload_lds16(const void* g, void* l) {
  __builtin_amdgcn_global_load_lds(
      (const __attribute__((address_space(1))) unsigned int*)g,
      (__attribute__((address_space(3))) unsigned int*)l, 16, 0, 0);
}
__device__ __forceinline__ float sigm_fast(float x) { return 1.f / (1.f + __expf(-x)); }

// plain CACHED 16B load with compile-time byte offset (no wait; counted vmcnt)
#define ISSUE_LD16C(dst, ptr, off)                                      \
  asm volatile("global_load_dwordx4 %0, %1, off offset:%c2"             \
               : "=v"(dst) : "v"(ptr), "i"(off) : "memory")

// plain cached 8B load (vmcnt-ordered among our asm ops)
#define LD8_PLAIN(dst, ptr)                                             \
  asm volatile("global_load_dwordx2 %0, %1, off"                        \
               : "=v"(dst) : "v"(ptr) : "memory")

// device-coherent 8B write-through store (to MALL home)
#define ST8_WT(ptr, val)                                                \
  asm volatile("global_store_dwordx2 %0, %1, off sc0 sc1"               \
               :: "v"(ptr), "v"(val) : "memory")

#define WAIT_VM16() do { asm volatile("s_waitcnt vmcnt(16)" ::: "memory"); \
                         __builtin_amdgcn_sched_barrier(0); } while (0)
#define WAIT_VM0()  do { asm volatile("s_waitcnt vmcnt(0)"  ::: "memory"); \
                         __builtin_amdgcn_sched_barrier(0); } while (0)

// ---------------- Phase 0 ----------------
__global__ void cast_f32_bf16(const float* __restrict__ src, u16* __restrict__ dst, int n4) {
  int i = blockIdx.x * blockDim.x + threadIdx.x;
  const int stride = gridDim.x * blockDim.x;
  for (; i < n4; i += stride) {
    float4 v = ((const float4*)src)[i];
    u16x4 o;
    o[0] = f2bf(v.x); o[1] = f2bf(v.y); o[2] = f2bf(v.z); o[3] = f2bf(v.w);
    ((u16x4*)dst)[i] = o;
  }
}

// diagnostic canary: out[0] = 100 (lstm_rec overwrites it at si=255)
__global__ void canary_k(float* __restrict__ out) { out[0] = 100.0f; }

// ---------------- Phase 1: pregate GEMM (proven, unchanged) ----------------
__global__ __launch_bounds__(256, 2) void gemm_pre(
    const u16* __restrict__ X, const u16* __restrict__ Wih,
    const float* __restrict__ bih, const float* __restrict__ bhh,
    u16* __restrict__ Pout)
{
  __shared__ u16 As[128 * 64];
  __shared__ u16 Bs[128 * 64];
  const int tid = threadIdx.x;
  const int lane = tid & 63;
  const int wid = tid >> 6;
  const int wm = wid & 1, wn = wid >> 1;
  const int Mt = blockIdx.x, Nt = blockIdx.y;

  f32x4 acc[4][4] = {};
  const int rsub = lane >> 3;
  const int src_chunk = (lane & 7) ^ rsub;

  for (int it = 0; it < 16; ++it) {
    const int k0 = it * 64;
    #pragma unroll
    for (int q = 0; q < 4; ++q) {
      const int j = wid * 4 + q;
      const int row_local = j * 8 + rsub;
      const u16* ga = X   + ((size_t)(Mt * 128 + row_local)) * 1024 + k0 + src_chunk * 8;
      const u16* gb = Wih + ((size_t)(Nt * 128 + row_local)) * 1024 + k0 + src_chunk * 8;
      gload_lds16(ga, (char*)As + j * 1024);
      gload_lds16(gb, (char*)Bs + j * 1024);
    }
    __syncthreads();
    #pragma unroll
    for (int ks = 0; ks < 2; ++ks) {
      short8 af[4], bfv[4];
      #pragma unroll
      for (int f = 0; f < 4; ++f) {
        const int ra = wm * 64 + f * 16 + (lane & 15);
        const int rb = wn * 64 + f * 16 + (lane & 15);
        const int kc = ks * 4 + (lane >> 4);
        af[f]  = *(const short8*)((const char*)As + ra * 128 + ((kc ^ (ra & 7)) << 4));
        bfv[f] = *(const short8*)((const char*)Bs + rb * 128 + ((kc ^ (rb & 7)) << 4));
      }
      #pragma unroll
      for (int fm = 0; fm < 4; ++fm)
        #pragma unroll
        for (int fn = 0; fn < 4; ++fn)
          acc[fm][fn] = __builtin_amdgcn_mfma_f32_16x16x32_bf16(af[fm], bfv[fn], acc[fm][fn], 0, 0, 0);
    }
    __syncthreads();
  }

  const int t_out = Mt * 2 + wm;
  #pragma unroll
  for (int fn = 0; fn < 4; ++fn) {
    const int n = Nt * 128 + wn * 64 + fn * 16 + (lane & 15);
    const float bias = bih[n] + bhh[n];
    #pragma unroll
    for (int fm = 0; fm < 4; ++fm) {
      const int b = fm * 16 + ((lane >> 4) << 2);
      u16x4 o;
      #pragma unroll
      for (int r = 0; r < 4; ++r) o[r] = f2bf(acc[fm][fn][r] + bias);
      *(u16x4*)(Pout + ((size_t)t_out * 4096 + n) * 64 + b) = o;
    }
  }
}

// ---------------- Phase 2: persistent recurrence ----------------
// Static LDS = 131072 + 16384 = 147456 B. Regular launch, 64 WGs (co-resident).
__global__ __launch_bounds__(256, 1) void lstm_rec(
    const u16* __restrict__ P, const float* __restrict__ c0,
    const float* __restrict__ Whh, u16* __restrict__ ring,
    float* __restrict__ out, int* __restrict__ flags)
{
  __shared__ u16 Ws[64 * 1024];
  __shared__ float GX[4096];     // gate exchange; first 2KB reused as HXu

  const int tid = threadIdx.x;
  const int lane = tid & 63;
  const int wid = tid >> 6;
  const int wg = blockIdx.x;

  // one-time W_hh slice -> LDS (bf16, XOR-swizzled rows)  [R7 verbatim]
  {
    const int rowp = tid >> 2;
    const int q = tid & 3;
    const int grow = (rowp >> 4) * 1024 + wg * 16 + (rowp & 15);
    const float4* src = (const float4*)(Whh + (size_t)grow * 1024 + q * 256);
    #pragma unroll 2
    for (int j = 0; j < 32; ++j) {
      float4 v0 = src[j * 2];
      float4 v1 = src[j * 2 + 1];
      short8 pk;
      pk[0] = (short)f2bf(v0.x); pk[1] = (short)f2bf(v0.y);
      pk[2] = (short)f2bf(v0.z); pk[3] = (short)f2bf(v0.w);
      pk[4] = (short)f2bf(v1.x); pk[5] = (short)f2bf(v1.y);
      pk[6] = (short)f2bf(v1.z); pk[7] = (short)f2bf(v1.w);
      const int kc = q * 32 + j;
      *(short8*)((char*)Ws + rowp * 2048 + ((kc ^ (rowp & 7)) << 4)) = pk;
    }
  }

  // pointwise role: unit u, batches b0..b0+3  [R7 verbatim]
  const int u = tid & 15;
  const int b0 = (tid >> 4) << 2;
  const int jh = wg * 16 + u;
  float cs[4];
  #pragma unroll
  for (int r = 0; r < 4; ++r) cs[r] = c0[(size_t)(b0 + r) * 1024 + jh];

  // h-publish role: row srow (batch), 8B chunk sq  [R7 verbatim]
  const int srow = tid >> 2;
  const int sq = tid & 3;

  const int wm = wid & 1;
  const int wn = wid >> 1;

  u16* HXu = (u16*)GX;

  __syncthreads();

  #define ISSUE_Q(buf, qi) {                                                   \
    _Pragma("unroll")                                                          \
    for (int kq_ = 0; kq_ < 8; ++kq_) {                                        \
      ISSUE_LD16C(buf[kq_][0], pA0, (qi) * 512 + kq_ * 64);                    \
      ISSUE_LD16C(buf[kq_][1], pA1, (qi) * 512 + kq_ * 64);                    \
    } }

  #define MFMA_Q(buf, qi) {                                                    \
    _Pragma("unroll")                                                          \
    for (int kq_ = 0; kq_ < 8; ++kq_) {                                        \
      const int kabs_ = (qi) * 8 + kq_;                                        \
      _Pragma("unroll")                                                        \
      for (int ni_ = 0; ni_ < 2; ++ni_) {                                      \
        const int rs_ = wn * 32 + ni_ * 16 + (lane & 15);                      \
        const int kcl_ = kabs_ * 4 + (lane >> 4);                              \
        const short8 bfr_ = *(const short8*)((const char*)Ws + rs_ * 2048      \
                            + ((kcl_ ^ (rs_ & 7)) << 4));                      \
        acc[0][ni_] = __builtin_amdgcn_mfma_f32_16x16x32_bf16(buf[kq_][0], bfr_, acc[0][ni_], 0, 0, 0); \
        acc[1][ni_] = __builtin_amdgcn_mfma_f32_16x16x32_bf16(buf[kq_][1], bfr_, acc[1][ni_], 0, 0, 0); \
      } } }

  for (int si = 0; si < 256; ++si) {
    const int t = 255 - si;
    const u16* rb = ring + (size_t)si * 65536;

    const u16* pA0 = rb + (size_t)(wm * 32 +  0 + (lane & 15)) * 1024 + ((lane >> 4) << 3);
    const u16* pA1 = rb + (size_t)(wm * 32 + 16 + (lane & 15)) * 1024 + ((lane >> 4) << 3);

    // P loads (asm 8B, oldest in vmcnt order)  [R7 verbatim]
    const size_t pbase = (size_t)t * 262144;
    unsigned long long Pi, Pf, Pg, Po;
    LD8_PLAIN(Pi, P + pbase + (size_t)(0 * 1024 + jh) * 64 + b0);
    LD8_PLAIN(Pf, P + pbase + (size_t)(1 * 1024 + jh) * 64 + b0);
    LD8_PLAIN(Pg, P + pbase + (size_t)(2 * 1024 + jh) * 64 + b0);
    LD8_PLAIN(Po, P + pbase + (size_t)(3 * 1024 + jh) * 64 + b0);

    f32x4 acc[2][2] = {};
    short8 afrA[8][2], afrB[8][2];

    // counted-vmcnt quarter pipeline  [R7 verbatim; robust to older outstanding
    // ys stores from the previous step by oldest-first vmcnt retirement]
    ISSUE_Q(afrA, 0)
    ISSUE_Q(afrB, 1)
    WAIT_VM16(); MFMA_Q(afrA, 0)
    ISSUE_Q(afrA, 2)
    WAIT_VM16(); MFMA_Q(afrB, 1)
    ISSUE_Q(afrB, 3)
    WAIT_VM16(); MFMA_Q(afrA, 2)
    WAIT_VM0();  MFMA_Q(afrB, 3)

    // gate exchange through LDS  [R7 verbatim]
    #pragma unroll
    for (int mi = 0; mi < 2; ++mi)
      #pragma unroll
      for (int ni = 0; ni < 2; ++ni) {
        const int g = wn * 2 + ni;
        const int uu = lane & 15;
        const int bb = wm * 32 + mi * 16 + ((lane >> 4) << 2);
        *(f32x4*)((char*)GX + ((((g * 16 + uu) * 64 + bb) << 2) ^ ((uu & 7) << 4))) = acc[mi][ni];
      }
    __syncthreads();

    const f32x4 vi = *(const f32x4*)((char*)GX + ((((0 * 16 + u) * 64 + b0) << 2) ^ ((u & 7) << 4)));
    const f32x4 vf = *(const f32x4*)((char*)GX + ((((1 * 16 + u) * 64 + b0) << 2) ^ ((u & 7) << 4)));
    const f32x4 vg = *(const f32x4*)((char*)GX + ((((2 * 16 + u) * 64 + b0) << 2) ^ ((u & 7) << 4)));
    const f32x4 vo = *(const f32x4*)((char*)GX + ((((3 * 16 + u) * 64 + b0) << 2) ^ ((u & 7) << 4)));

    float hvv[4], cnn[4];
    #pragma unroll
    for (int r = 0; r < 4; ++r) {
      const float xi = vi[r] + bf2f((u16)(Pi >> (16 * r)));
      const float xf = vf[r] + bf2f((u16)(Pf >> (16 * r)));
      const float xg = vg[r] + bf2f((u16)(Pg >> (16 * r)));
      const float xo = vo[r] + bf2f((u16)(Po >> (16 * r)));
      const float ig = sigm_fast(xi);
      const float fg = sigm_fast(xf);
      const float og = sigm_fast(xo);
      const float cn = fg * cs[r] + ig * tanhf(xg);
      const float hv = og * tanhf(cn);
      cs[r] = cn; cnn[r] = cn; hvv[r] = hv;
    }

    if (si < 255) {
      __syncthreads();  // all GX gate reads done; safe to overwrite with HXu
      #pragma unroll
      for (int r = 0; r < 4; ++r) HXu[(b0 + r) * 16 + u] = f2bf(hvv[r]);
      __syncthreads();  // HXu complete
      // coalesced 8B write-through publish: straight to MALL, no dirty L2 lines
      {
        u16* wb = ring + (size_t)(si + 1) * 65536;
        const unsigned long long hv8 = *(const unsigned long long*)(HXu + srow * 16 + sq * 4);
        ST8_WT(wb + (size_t)srow * 1024 + wg * 16 + sq * 4, hv8);
      }
      WAIT_VM0();        // drain covers ONLY the 2KB publish (ys not yet issued)
      __syncthreads();   // whole WG drained
      if (tid == 0) atomicAdd(&flags[wg << 5], 1);   // 1 flag per 128B line
      // ys stores AFTER the flag — acks retire under the poll
      #pragma unroll
      for (int r = 0; r < 4; ++r)
        out[((size_t)t * 64 + b0 + r) * 1024 + jh] = hvv[r];
      if (tid < 64) {
        while (__hip_atomic_load(&flags[tid << 5], __ATOMIC_RELAXED, __HIP_MEMORY_SCOPE_AGENT) < si + 1)
          __builtin_amdgcn_s_sleep(2);
      }
      __syncthreads();
    } else {
      #pragma unroll
      for (int r = 0; r < 4; ++r) {
        out[((size_t)t * 64 + b0 + r) * 1024 + jh] = hvv[r];            // ys t=0
        out[YS_ELEMS + (size_t)(b0 + r) * 1024 + jh] = hvv[r];          // hT
        out[YS_ELEMS + 65536 + (size_t)(b0 + r) * 1024 + jh] = cnn[r];  // cT
      }
    }
  }
  #undef ISSUE_Q
  #undef MFMA_Q
}

// ---------------- launch ----------------
extern "C" void kernel_launch(void* const* d_in, const int* in_sizes, int n_in,
                              void* d_out, int out_size, void* d_ws, size_t ws_size,
                              hipStream_t stream) {
  const float* x   = (const float*)d_in[0];
  const float* h0  = (const float*)d_in[1];
  const float* c0  = (const float*)d_in[2];
  const float* Wih = (const float*)d_in[3];
  const float* Whh = (const float*)d_in[4];
  const float* bih = (const float*)d_in[5];
  const float* bhh = (const float*)d_in[6];
  float* out = (float*)d_out;

  char* ws = (char*)d_ws;
  u16* x_bf   = (u16*)(ws + 0);           // 32MB; recycled as h ring after gemm_pre
  u16* ring   = (u16*)(ws + 0);           // 256 x 131072 B
  u16* wih_bf = (u16*)(ws + 33554432);
  u16* Pp     = (u16*)(ws + 41943040);    // 128MB
  int* flags  = (int*)(ws + 176160768);   // 8KB (64 flags, 128B-padded)

  hipLaunchKernelGGL(cast_f32_bf16, dim3(2048), dim3(256), 0, stream, x,   x_bf,   4194304);
  hipLaunchKernelGGL(cast_f32_bf16, dim3(1024), dim3(256), 0, stream, Wih, wih_bf, 1048576);
  hipLaunchKernelGGL(gemm_pre, dim3(128, 32), dim3(256), 0, stream, x_bf, wih_bf, bih, bhh, Pp);
  hipMemsetAsync(flags, 0, 8192, stream);
  hipLaunchKernelGGL(cast_f32_bf16, dim3(64), dim3(256), 0, stream, h0, ring, 16384);
  hipLaunchKernelGGL(canary_k, dim3(1), dim3(1), 0, stream, out);

  // REGULAR launch (not cooperative): 64 WGs, 1/CU -> trivially co-resident.
  hipLaunchKernelGGL(lstm_rec, dim3(64), dim3(256), 0, stream,
                     (const u16*)Pp, c0, Whh, ring, out, flags);
}